// Round 1
// baseline (561.083 us; speedup 1.0000x reference)
//
#include <hip/hip_runtime.h>
#include <math.h>

#define M_ROWS 16384
#define DIM 1024

#define BM 128
#define BN 128
#define BK 32
#define APAD 132   // 128 + 4: keeps float4 alignment, breaks worst bank conflicts

__device__ __forceinline__ float waveReduceSum(float v) {
#pragma unroll
    for (int off = 32; off > 0; off >>= 1) v += __shfl_down(v, off, 64);
    return v;
}

// ---- column norms of weigh_v (axis=0), two-stage for parallelism ----
__global__ void colnorm_partial(const float* __restrict__ W, float* __restrict__ part) {
    // grid 32: (blockIdx.x & 3) -> column block of 256, (blockIdx.x >> 2) -> row block of 128
    int col = (blockIdx.x & 3) * 256 + threadIdx.x;
    int r0 = (blockIdx.x >> 2) * 128;
    float s = 0.f;
#pragma unroll 8
    for (int i = 0; i < 128; ++i) {
        float t = W[(size_t)(r0 + i) * DIM + col];
        s += t * t;
    }
    part[(size_t)(blockIdx.x >> 2) * DIM + col] = s;
}

__global__ void colnorm_final(const float* __restrict__ part, float* __restrict__ invn) {
    int col = blockIdx.x * 256 + threadIdx.x;
    float s = 0.f;
#pragma unroll
    for (int p = 0; p < 8; ++p) s += part[(size_t)p * DIM + col];
    float n = fminf(fmaxf(sqrtf(s), 1e-6f), 1e6f);
    invn[col] = 1.0f / n;
}

// ---- per-row prep: rowscale (expmap0+proj+rc folded) and cx2 ----
__global__ void rowprep(const float* __restrict__ in, const float* __restrict__ cptr,
                        float* __restrict__ rowscale, float* __restrict__ cx2) {
    int row = blockIdx.x;
    const float4* rp = (const float4*)(in + (size_t)row * DIM);
    float4 v = rp[threadIdx.x];
    float s = v.x * v.x + v.y * v.y + v.z * v.z + v.w * v.w;
    s = waveReduceSum(s);
    __shared__ float red[4];
    int wid = threadIdx.x >> 6, lane = threadIdx.x & 63;
    if (lane == 0) red[wid] = s;
    __syncthreads();
    if (threadIdx.x == 0) {
        float stot = red[0] + red[1] + red[2] + red[3];
        float c = cptr[0];
        float rc = sqrtf(c);
        float un = sqrtf(fmaxf(stot, 1e-15f));           // _safe_norm(u)
        float xscale = tanhf(rc * un) / (rc * un);       // x = xscale * u
        float xn = sqrtf(fmaxf(xscale * xscale * stot, 1e-15f));  // _safe_norm(x)
        float maxnorm = (1.0f - 1e-5f) / rc;
        float pf = (xn > maxnorm) ? (maxnorm / xn) : 1.0f;       // proj
        float rsv = rc * xscale * pf;                    // rcx = rsv * u
        rowscale[row] = rsv;
        cx2[row] = rsv * rsv * stot;                     // sum(rcx^2), unclipped
    }
}

// ---- main GEMM: acc = rcx @ w  (invn/cosh/sinh/asinh/sinh folded into epilogue) ----
__global__ __launch_bounds__(256) void gemm_epi(
    const float* __restrict__ A, const float* __restrict__ W,
    const float* __restrict__ rowscale, const float* __restrict__ cx2,
    const float* __restrict__ invn, const float* __restrict__ wg,
    const float* __restrict__ bias, const float* __restrict__ cptr,
    float* __restrict__ Y) {
    __shared__ float As[BK][APAD];   // transposed A tile: As[k][r]
    __shared__ float Bs[BK][BN];

    const int t = threadIdx.x;
    const int tx = t & 15, ty = t >> 4;
    const int row0 = blockIdx.y * BM;
    const int col0 = blockIdx.x * BN;

    const int lr = t >> 3;           // 0..31 (A-load row within pass)
    const int lk = (t & 7) * 4;      // 0,4..28 (A-load k)
    const int kb = t >> 5;           // 0..7  (B-load k within pass)
    const int cb = (t & 31) * 4;     // 0..124 (B-load col)

    float rs[4];
#pragma unroll
    for (int p = 0; p < 4; ++p) rs[p] = rowscale[row0 + lr + p * 32];

    float acc[8][8];
#pragma unroll
    for (int i = 0; i < 8; ++i)
#pragma unroll
        for (int j = 0; j < 8; ++j) acc[i][j] = 0.f;

    for (int k0 = 0; k0 < DIM; k0 += BK) {
#pragma unroll
        for (int p = 0; p < 4; ++p) {
            int r = lr + p * 32;
            float4 v = *(const float4*)(A + (size_t)(row0 + r) * DIM + k0 + lk);
            As[lk + 0][r] = v.x * rs[p];
            As[lk + 1][r] = v.y * rs[p];
            As[lk + 2][r] = v.z * rs[p];
            As[lk + 3][r] = v.w * rs[p];
        }
#pragma unroll
        for (int p = 0; p < 4; ++p) {
            int k = kb + p * 8;
            *(float4*)&Bs[k][cb] = *(const float4*)(W + (size_t)(k0 + k) * DIM + col0 + cb);
        }
        __syncthreads();
#pragma unroll
        for (int k = 0; k < BK; ++k) {
            float4 a0 = *(const float4*)&As[k][ty * 4];
            float4 a1 = *(const float4*)&As[k][64 + ty * 4];
            float4 b0 = *(const float4*)&Bs[k][tx * 4];
            float4 b1 = *(const float4*)&Bs[k][64 + tx * 4];
            float av[8] = {a0.x, a0.y, a0.z, a0.w, a1.x, a1.y, a1.z, a1.w};
            float bv[8] = {b0.x, b0.y, b0.z, b0.w, b1.x, b1.y, b1.z, b1.w};
#pragma unroll
            for (int i = 0; i < 8; ++i)
#pragma unroll
                for (int j = 0; j < 8; ++j)
                    acc[i][j] = fmaf(av[i], bv[j], acc[i][j]);
        }
        __syncthreads();
    }

    // epilogue: mlr -> w -> y (store y; row-dependent denominator handled later)
    const float c = cptr[0];
    const float rcv = sqrtf(c);
    const float inv_rc = 1.0f / rcv;

    float cxr[8];
#pragma unroll
    for (int ib = 0; ib < 2; ++ib)
#pragma unroll
        for (int i = 0; i < 4; ++i)
            cxr[ib * 4 + i] = cx2[row0 + ib * 64 + ty * 4 + i];

#pragma unroll
    for (int jb = 0; jb < 2; ++jb) {
        int cbase = col0 + jb * 64 + tx * 4;
        float4 iv = *(const float4*)(invn + cbase);
        float4 gv = *(const float4*)(wg + cbase);
        float4 bv = *(const float4*)(bias + cbase);
        float ivv[4] = {iv.x, iv.y, iv.z, iv.w};
        float gvv[4] = {gv.x, gv.y, gv.z, gv.w};
        float bvv[4] = {bv.x, bv.y, bv.z, bv.w};
        float chf[4], shf[4], wff[4];
#pragma unroll
        for (int j = 0; j < 4; ++j) {
            float dr = 2.0f * rcv * bvv[j];
            chf[j] = coshf(dr) * 2.0f * ivv[j];   // folds the 2*invn factor
            shf[j] = sinhf(dr);
            wff[j] = 2.0f * gvv[j] * inv_rc;
        }
#pragma unroll
        for (int ib = 0; ib < 2; ++ib) {
#pragma unroll
            for (int i = 0; i < 4; ++i) {
                int r = row0 + ib * 64 + ty * 4 + i;
                float4 o;
                float* op = &o.x;
#pragma unroll
                for (int j = 0; j < 4; ++j) {
                    float a = acc[ib * 4 + i][jb * 4 + j];
                    float mlr = a * chf[j] - (1.0f + cxr[ib * 4 + i]) * shf[j];
                    float wv = wff[j] * asinhf(mlr);
                    op[j] = sinhf(rcv * wv) * inv_rc;
                }
                *(float4*)(Y + (size_t)r * DIM + cbase) = o;
            }
        }
    }
}

// ---- per-row finalize: denom + relu-in-tangent + logmap0, all scalar factors ----
__global__ void finalize(float* __restrict__ Y, const float* __restrict__ cptr) {
    int row = blockIdx.x;
    float4* rp = (float4*)(Y + (size_t)row * DIM);
    float4 v = rp[threadIdx.x];
    float s1 = v.x * v.x + v.y * v.y + v.z * v.z + v.w * v.w;
    float rx = fmaxf(v.x, 0.f), ryy = fmaxf(v.y, 0.f);
    float rz = fmaxf(v.z, 0.f), rw = fmaxf(v.w, 0.f);
    float s2 = rx * rx + ryy * ryy + rz * rz + rw * rw;
    s1 = waveReduceSum(s1);
    s2 = waveReduceSum(s2);
    __shared__ float red1[4], red2[4];
    int wid = threadIdx.x >> 6, lane = threadIdx.x & 63;
    if (lane == 0) { red1[wid] = s1; red2[wid] = s2; }
    __syncthreads();
    s1 = red1[0] + red1[1] + red1[2] + red1[3];
    s2 = red2[0] + red2[1] + red2[2] + red2[3];

    const float c = cptr[0];
    const float rc = sqrtf(c);
    float g = 1.0f / (1.0f + sqrtf(1.0f + c * s1));     // x = g*y
    float xn = sqrtf(fmaxf(g * g * s1, 1e-15f));
    float arg = fminf(rc * xn, 1.0f - 1e-7f);
    float f1 = atanhf(arg) / (rc * xn);                  // u = f1*x
    float fv = f1 * g;                                   // v = fv*relu(y), fv>=0
    float vn = sqrtf(fmaxf(fv * fv * s2, 1e-15f));
    float f2 = tanhf(rc * vn) / (rc * vn);               // e = f2*v
    float en = sqrtf(fmaxf(f2 * f2 * fv * fv * s2, 1e-15f));
    float maxnorm = (1.0f - 1e-5f) / rc;
    float pf = (en > maxnorm) ? (maxnorm / en) : 1.0f;   // z = pf*e
    float zn = sqrtf(fmaxf(pf * pf * f2 * f2 * fv * fv * s2, 1e-15f));
    float arg2 = fminf(rc * zn, 1.0f - 1e-7f);
    float f3 = atanhf(arg2) / (rc * zn);                 // out = f3*z
    float F = f3 * pf * f2 * fv;

    float4 o = make_float4(F * rx, F * ryy, F * rz, F * rw);
    rp[threadIdx.x] = o;
}

extern "C" void kernel_launch(void* const* d_in, const int* in_sizes, int n_in,
                              void* d_out, int out_size, void* d_ws, size_t ws_size,
                              hipStream_t stream) {
    const float* inputs   = (const float*)d_in[0];
    const float* weigh_v  = (const float*)d_in[1];
    const float* weight_g = (const float*)d_in[2];
    const float* bias     = (const float*)d_in[3];
    const float* cptr     = (const float*)d_in[4];
    float* Y = (float*)d_out;

    float* ws       = (float*)d_ws;
    float* invn     = ws;                        // 1024
    float* rowscale = ws + 1024;                 // 16384
    float* cx2      = ws + 1024 + 16384;         // 16384
    float* colpart  = ws + 1024 + 2 * 16384;     // 8*1024

    colnorm_partial<<<32, 256, 0, stream>>>(weigh_v, colpart);
    colnorm_final<<<4, 256, 0, stream>>>(colpart, invn);
    rowprep<<<M_ROWS, 256, 0, stream>>>(inputs, cptr, rowscale, cx2);

    dim3 grid(DIM / BN, M_ROWS / BM);
    gemm_epi<<<grid, 256, 0, stream>>>(inputs, weigh_v, rowscale, cx2, invn,
                                       weight_g, bias, cptr, Y);

    finalize<<<M_ROWS, 256, 0, stream>>>(Y, cptr);
}